// Round 1
// 362.923 us; speedup vs baseline: 1.0357x; 1.0357x over previous
//
#include <hip/hip_runtime.h>

#define NNODES 4096
#define NCH    128
#define NE     10

// ---------------- workspace layout (float elements) ----------------
// [0..16)    counts (int)
// [16..32)   cursor (int)
// [48..4144) list (int, q -> b)
// 4160:      Sws [e][c][2048]  packed symmetric tables (2,621,440)
//            per (e,c): 9 D-streams at stride 224, each 219 floats:
//            for i: {T1_i; for j>=i: {S2_ij; for n>=j: S3_ijn}}
// then       pre  [c][D][q]    (4,718,592)
// then       xg   [c][n][q]    (4,718,592)
// total ~48.3 MB

// ---------------- symmetric-stream decode table ----------------
struct MTab { unsigned short v[220]; };
static constexpr MTab make_mtab() {
    MTab t{};
    int m = 0;
    for (int i = 0; i < 9; ++i) {
        t.v[m++] = (unsigned short)((1 << 12) | (i << 8) | (i << 4) | i);
        for (int j = i; j < 9; ++j) {
            t.v[m++] = (unsigned short)((2 << 12) | (i << 8) | (j << 4) | j);
            for (int n = j; n < 9; ++n)
                t.v[m++] = (unsigned short)((3 << 12) | (i << 8) | (j << 4) | n);
        }
    }
    return t;   // m == 219
}
__constant__ MTab c_mtab = make_mtab();

// ---------------- bucketing ----------------
__global__ void k_count(const float* __restrict__ attrs, int* __restrict__ counts)
{
    int b = blockIdx.x * 256 + threadIdx.x;
    if (b >= NNODES) return;
    const float* y = attrs + (size_t)b * NE;
    int e = 0;
#pragma unroll
    for (int t = 0; t < NE; ++t) if (y[t] > 0.5f) e = t;
    atomicAdd(&counts[e], 1);
}

__global__ void k_scatter(const float* __restrict__ attrs, const int* __restrict__ counts,
                          int* __restrict__ cursor, int* __restrict__ list)
{
    int b = blockIdx.x * 256 + threadIdx.x;
    if (b >= NNODES) return;
    const float* y = attrs + (size_t)b * NE;
    int e = 0;
#pragma unroll
    for (int t = 0; t < NE; ++t) if (y[t] > 0.5f) e = t;
    int off = 0;
#pragma unroll
    for (int u = 0; u < NE; ++u) off += (u < e) ? counts[u] : 0;
    int pos = atomicAdd(&cursor[e], 1);
    list[off + pos] = b;
}

// 30-wide dot of one U3 row with per-lane w3
__device__ __forceinline__ float dot30(const float* __restrict__ U3, int dloc, int row,
                                       const float (&w3)[30])
{
    const float2* u = (const float2*)(U3 + ((size_t)dloc * 729 + row) * 30);
    float v = 0.0f;
#pragma unroll
    for (int kk = 0; kk < 15; ++kk) {
        float2 a = u[kk];
        v = fmaf(a.x, w3[2 * kk], v);
        v = fmaf(a.y, w3[2 * kk + 1], v);
    }
    return v;
}

// ---------------- fused gather + symmetric table precompute ----------------
// blocks [0,512): gather-transpose (needs list)
// blocks [512,1142): symmetric tables: (e, D, 32-entry chunk of the 219-stream)
__global__ __launch_bounds__(256) void k_gp(
    const float* __restrict__ nf, const int* __restrict__ list,
    const float* __restrict__ U3_0, const float* __restrict__ U3_1, const float* __restrict__ U3_2,
    const float* __restrict__ W3_0, const float* __restrict__ W3_1, const float* __restrict__ W3_2,
    const float* __restrict__ U2_0, const float* __restrict__ U2_1, const float* __restrict__ U2_2,
    const float* __restrict__ W2_0, const float* __restrict__ W2_1, const float* __restrict__ W2_2,
    const float* __restrict__ U1_0, const float* __restrict__ U1_1, const float* __restrict__ U1_2,
    const float* __restrict__ W1_0, const float* __restrict__ W1_1, const float* __restrict__ W1_2,
    float* __restrict__ xg, float* __restrict__ Sws)
{
    __shared__ __align__(16) float smem[64 * 145];
    __shared__ int lb[64];
    int bid = blockIdx.x, t = threadIdx.x;
    if (bid < 512) {
        // ---- gather-transpose: xg[(c*9+n)*4096+q] = nf[(list[q]*128+c)*9+n] ----
        int qb = bid >> 3, ct = bid & 7;
        int c0 = ct * 16;
        if (t < 64) lb[t] = list[qb * 64 + t];
        __syncthreads();
#pragma unroll 1
        for (int k = 0; k < 36; ++k) {
            int idx = k * 256 + t;                // 64 nodes * 144 elems
            int node = idx / 144, elem = idx - node * 144;
            smem[node * 145 + elem] = nf[((size_t)lb[node] * 128 + c0) * 9 + elem];
        }
        __syncthreads();
#pragma unroll 1
        for (int k = 0; k < 36; ++k) {
            int idx = k * 256 + t;
            int node = idx & 63, re = idx >> 6;
            xg[((size_t)(c0 * 9 + re)) * NNODES + qb * 64 + node] = smem[node * 145 + re];
        }
    } else {
        // ---- symmetric table build: one (e, D), 32 stream entries x 128 c ----
        int bid2 = bid - 512;
        int e = bid2 / 63, r = bid2 - e * 63;
        int D = r / 7, chunk0 = (r - D * 7) * 32;
        int c = t & 127, sub = t >> 7;
        const float *U3, *U2, *U1, *W3, *W2, *W1; int dloc;
        if (D == 0)      { U3 = U3_0; U2 = U2_0; U1 = U1_0; W3 = W3_0; W2 = W2_0; W1 = W1_0; dloc = 0; }
        else if (D < 4)  { U3 = U3_1; U2 = U2_1; U1 = U1_1; W3 = W3_1; W2 = W2_1; W1 = W1_1; dloc = D - 1; }
        else             { U3 = U3_2; U2 = U2_2; U1 = U1_2; W3 = W3_2; W2 = W2_2; W1 = W1_2; dloc = D - 4; }
        float w3[30], w2[12], w1[4];
#pragma unroll
        for (int k = 0; k < 30; ++k) w3[k] = W3[((size_t)e * 30 + k) * 128 + c];
#pragma unroll
        for (int k = 0; k < 12; ++k) w2[k] = W2[((size_t)e * 12 + k) * 128 + c];
#pragma unroll
        for (int k = 0; k < 4; ++k)  w1[k] = W1[((size_t)e * 4 + k) * 128 + c];
        float* tile = smem;                       // 32*129 floats used
#pragma unroll 1
        for (int rr = sub * 16; rr < sub * 16 + 16; ++rr) {
            int m = chunk0 + rr;
            float val = 0.0f;
            if (m < 219) {
                unsigned mv = c_mtab.v[m];
                int kind = mv >> 12, i = (mv >> 8) & 15, j = (mv >> 4) & 15, n = mv & 15;
                if (kind == 1) {
                    const float* u = U1 + (size_t)(dloc * 9 + i) * 4;
#pragma unroll
                    for (int k = 0; k < 4; ++k) val = fmaf(u[k], w1[k], val);
                } else if (kind == 2) {
                    const float* ua = U2 + (size_t)(dloc * 81 + i * 9 + j) * 12;
#pragma unroll
                    for (int k = 0; k < 12; ++k) val = fmaf(ua[k], w2[k], val);
                    if (i != j) {
                        const float* ub = U2 + (size_t)(dloc * 81 + j * 9 + i) * 12;
#pragma unroll
                        for (int k = 0; k < 12; ++k) val = fmaf(ub[k], w2[k], val);
                    }
                } else {
                    // orbit of (i<=j<=n): 1, 3, or 6 distinct permutations
                    int r1 = -1, r2 = -1, r3 = -1, r4 = -1, r5 = -1;
                    if (i == j) {
                        if (j != n) { r1 = i * 81 + n * 9 + i; r2 = n * 81 + i * 9 + i; }
                    } else if (j == n) {
                        r1 = j * 81 + i * 9 + j; r2 = j * 81 + j * 9 + i;
                    } else {
                        r1 = i * 81 + n * 9 + j; r2 = j * 81 + i * 9 + n;
                        r3 = j * 81 + n * 9 + i; r4 = n * 81 + i * 9 + j;
                        r5 = n * 81 + j * 9 + i;
                    }
                    val = dot30(U3, dloc, i * 81 + j * 9 + n, w3);
                    if (r1 >= 0) { val += dot30(U3, dloc, r1, w3); val += dot30(U3, dloc, r2, w3); }
                    if (r3 >= 0) {
                        val += dot30(U3, dloc, r3, w3); val += dot30(U3, dloc, r4, w3);
                        val += dot30(U3, dloc, r5, w3);
                    }
                }
            }
            tile[rr * 129 + c] = val;
        }
        __syncthreads();
#pragma unroll 1
        for (int wv = 0; wv < 16; ++wv) {
            int idx = t + 256 * wv;               // 32 entries * 128 c = 4096
            int cc = idx >> 5, rr = idx & 31;
            int m = chunk0 + rr;
            if (m < 219)
                Sws[((size_t)e * 128 + cc) * 2048 + D * 224 + m] = tile[rr * 129 + cc];
        }
    }
}

// ---------------- main contraction (triangular symmetric Horner) ----------------
// out = sum_i x_i*(T1_i + sum_{j>=i} x_j*(S2_ij + sum_{n>=j} S3_ijn*x_n))
// 219 FMAs per (q,D) vs 819 for the dense nest. Tables read sequentially
// per D (wave-uniform -> s_load), amortized over NB node chunks.
template <int NB>
__device__ __forceinline__ void eq_chunk(
    const float* __restrict__ xq, const float* __restrict__ tab,
    float* __restrict__ preq, int cb, int cnt, int lane, int dbase)
{
    float x[NB][9];
#pragma unroll
    for (int t = 0; t < NB; ++t) {
        int pos = cb + t * 64 + lane;
        bool v = pos < cnt;
        int p = v ? pos : 0;
#pragma unroll
        for (int n = 0; n < 9; ++n)
            x[t][n] = v ? xq[(size_t)n * NNODES + p] : 0.0f;
    }
#pragma unroll 1
    for (int dd = 0; dd < 3; ++dd) {
        int D = dbase + dd;
        const float* s = tab + D * 224;
        float acc3[NB];
#pragma unroll
        for (int t = 0; t < NB; ++t) acc3[t] = 0.0f;
        int p = 0;
#pragma unroll
        for (int i = 0; i < 9; ++i) {
            float t1v = s[p++];
            float acc2[NB];
#pragma unroll
            for (int t = 0; t < NB; ++t) acc2[t] = t1v;
#pragma unroll
            for (int j = i; j < 9; ++j) {
                float t2v = s[p++];
                float acc1[NB];
#pragma unroll
                for (int t = 0; t < NB; ++t) acc1[t] = t2v;
#pragma unroll
                for (int n = j; n < 9; ++n) {
                    float t3v = s[p++];
#pragma unroll
                    for (int t = 0; t < NB; ++t) acc1[t] = fmaf(t3v, x[t][n], acc1[t]);
                }
#pragma unroll
                for (int t = 0; t < NB; ++t) acc2[t] = fmaf(acc1[t], x[t][j], acc2[t]);
            }
#pragma unroll
            for (int t = 0; t < NB; ++t) acc3[t] = fmaf(acc2[t], x[t][i], acc3[t]);
        }
#pragma unroll
        for (int t = 0; t < NB; ++t) {
            int pos = cb + t * 64 + lane;
            if (pos < cnt)
                preq[(size_t)D * NNODES + pos] = acc3[t];
        }
    }
}

// grid (128 c, 10 e, 6 zd): zd = (znode in [0,2)) | (dgrp in [0,3)) -> 7680 waves ~30/CU.
__global__ __launch_bounds__(64, 6) void k_main(
    const float* __restrict__ xg, const int* __restrict__ counts,
    const float* __restrict__ Sws, float* __restrict__ pre)
{
    int c = blockIdx.x, e = blockIdx.y, zd = blockIdx.z;
    int znode = zd & 1, dbase = (zd >> 1) * 3;
    int lane = threadIdx.x;
    int cnt = counts[e];
    int qstart = 0;
#pragma unroll
    for (int u = 0; u < NE; ++u) qstart += (u < e) ? counts[u] : 0;
    const float* tab = Sws + ((size_t)e * NCH + c) * 2048;
    const float* xq = xg + (size_t)c * 9 * NNODES + qstart;
    float* preq = pre + (size_t)c * 9 * NNODES + qstart;

#pragma unroll 1
    for (int cb = znode * 256; cb < cnt; cb += 512) {
        int rem = cnt - cb;
        int nb = (rem + 63) >> 6;
        if (nb >= 4) {
            eq_chunk<4>(xq, tab, preq, cb, cnt, lane, dbase);
        } else if (nb == 3) {
            eq_chunk<3>(xq, tab, preq, cb, cnt, lane, dbase);
        } else if (nb == 2) {
            eq_chunk<2>(xq, tab, preq, cb, cnt, lane, dbase);
        } else {
            eq_chunk<1>(xq, tab, preq, cb, cnt, lane, dbase);
        }
    }
}

// ---------------- channel mix + permute + sc add (fused epilogue) ----------------
__global__ __launch_bounds__(256) void k_mixout(
    const float* __restrict__ pre, const int* __restrict__ list,
    const float* __restrict__ sc,
    const float* __restrict__ lin0, const float* __restrict__ lin1,
    const float* __restrict__ lin2, float* __restrict__ out)
{
    int qb = blockIdx.x, D = blockIdx.y;
    int t = threadIdx.x;
    int tq = t & 15, tf = t >> 4;
    int q0 = qb * 64 + tq * 4;
    int f0 = tf * 8;
    const float* lin; int L, dl;
    if (D == 0)      { lin = lin0; L = 0; dl = 0; }
    else if (D < 4)  { lin = lin1; L = 1; dl = D - 1; }
    else             { lin = lin2; L = 2; dl = D - 4; }

    float acc[4][8];
#pragma unroll
    for (int qi = 0; qi < 4; ++qi)
#pragma unroll
        for (int ff = 0; ff < 8; ++ff) acc[qi][ff] = 0.0f;

#pragma unroll 2
    for (int c = 0; c < 128; ++c) {
        float4 pv = *(const float4*)&pre[((size_t)c * 9 + D) * NNODES + q0];
        float4 la = *(const float4*)&lin[c * 128 + f0];
        float4 lb = *(const float4*)&lin[c * 128 + f0 + 4];
        float l[8] = {la.x, la.y, la.z, la.w, lb.x, lb.y, lb.z, lb.w};
        float p[4] = {pv.x, pv.y, pv.z, pv.w};
#pragma unroll
        for (int qi = 0; qi < 4; ++qi)
#pragma unroll
            for (int ff = 0; ff < 8; ++ff)
                acc[qi][ff] = fmaf(p[qi], l[ff], acc[qi][ff]);
    }

    const float nrm = 0.08838834764831845f;   // 1/sqrt(128)
#pragma unroll
    for (int qi = 0; qi < 4; ++qi) {
        int b = list[q0 + qi];
        float* ob = out + (size_t)b * 1152;
        const float* scb = sc + (size_t)b * 1152;
        if (L == 0) {
#pragma unroll
            for (int ff = 0; ff < 8; ++ff)
                ob[f0 + ff] = fmaf(nrm, acc[qi][ff], scb[f0 + ff]);
        } else if (L == 1) {
#pragma unroll
            for (int ff = 0; ff < 8; ++ff) {
                int col = 128 + (f0 + ff) * 3 + dl;
                ob[col] = fmaf(nrm, acc[qi][ff], scb[col]);
            }
        } else {
#pragma unroll
            for (int ff = 0; ff < 8; ++ff) {
                int col = 512 + (f0 + ff) * 5 + dl;
                ob[col] = fmaf(nrm, acc[qi][ff], scb[col]);
            }
        }
    }
}

// ---------------- launch ----------------
extern "C" void kernel_launch(void* const* d_in, const int* in_sizes, int n_in,
                              void* d_out, int out_size, void* d_ws, size_t ws_size,
                              hipStream_t stream)
{
    const float* nf    = (const float*)d_in[0];
    const float* sc    = (const float*)d_in[1];
    const float* attrs = (const float*)d_in[2];
    const float *U3s[3], *U2s[3], *U1s[3], *W3s[3], *W2s[3], *W1s[3], *lins[3];
    for (int L = 0; L < 3; ++L) {
        const int o = 3 + 7 * L;
        U3s[L]  = (const float*)d_in[o + 0];
        U2s[L]  = (const float*)d_in[o + 1];
        U1s[L]  = (const float*)d_in[o + 2];
        W3s[L]  = (const float*)d_in[o + 3];
        W2s[L]  = (const float*)d_in[o + 4];
        W1s[L]  = (const float*)d_in[o + 5];
        lins[L] = (const float*)d_in[o + 6];
    }

    float* wsf   = (float*)d_ws;
    int* counts  = (int*)d_ws;
    int* cursor  = counts + 16;
    int* list    = counts + 48;
    float* Sws = wsf + 4160;
    float* pre = Sws + (size_t)NE * NCH * 2048;     // 2,621,440
    float* xg  = pre + (size_t)NCH * 9 * NNODES;    // 4,718,592

    hipMemsetAsync(d_ws, 0, 128, stream);   // counts + cursor
    k_count  <<<16, 256, 0, stream>>>(attrs, counts);
    k_scatter<<<16, 256, 0, stream>>>(attrs, counts, cursor, list);
    k_gp<<<1142, 256, 0, stream>>>(nf, list,
                                   U3s[0], U3s[1], U3s[2], W3s[0], W3s[1], W3s[2],
                                   U2s[0], U2s[1], U2s[2], W2s[0], W2s[1], W2s[2],
                                   U1s[0], U1s[1], U1s[2], W1s[0], W1s[1], W1s[2],
                                   xg, Sws);
    k_main<<<dim3(128, 10, 6), 64, 0, stream>>>(xg, counts, Sws, pre);
    k_mixout<<<dim3(64, 9), 256, 0, stream>>>(pre, list, sc, lins[0], lins[1], lins[2], (float*)d_out);
}